// Round 20
// baseline (169.362 us; speedup 1.0000x reference)
//
#include <hip/hip_runtime.h>
#include <hip/hip_bf16.h>

typedef __attribute__((ext_vector_type(8))) short short8;
typedef __attribute__((ext_vector_type(8))) unsigned short ushort8;
typedef __attribute__((ext_vector_type(4))) unsigned short bf16x4;
typedef __attribute__((ext_vector_type(4))) float f32x4;

#define BDIM 1024
#define SEQ  2048
#define NHD  16
#define NEGBIG (-1.0e30f)

__device__ __forceinline__ unsigned short f2bf(float x) {
  union { __hip_bfloat16 h; unsigned short u; } cv;
  cv.h = __float2bfloat16(x);
  return cv.u;
}

__device__ __forceinline__ void gload16(const void* g, void* l) {
  __builtin_amdgcn_global_load_lds((const __attribute__((address_space(1))) void*)g,
                                   (__attribute__((address_space(3))) void*)l, 16, 0, 0);
}

// ---------------- fused prep: z=0..3 weight transpose+cvt; z=4..7 X f32->bf16 ----------
__global__ __launch_bounds__(256) void prep(const float* __restrict__ X, unsigned short* __restrict__ Xb,
                                            const float* __restrict__ s0, const float* __restrict__ s1,
                                            const float* __restrict__ s2, const float* __restrict__ s3,
                                            unsigned short* __restrict__ d0, unsigned short* __restrict__ d1,
                                            unsigned short* __restrict__ d2, unsigned short* __restrict__ d3) {
  const int z = blockIdx.z;
  const int tid = threadIdx.y * 32 + threadIdx.x;
  if (z >= 4) {  // cvt: 1024 blocks/slice x 2048 elems
    int i = (((z - 4) * 1024 + blockIdx.y * 32 + blockIdx.x) * 256 + tid) * 8;
    float4 a = *(const float4*)(X + i);
    float4 b = *(const float4*)(X + i + 4);
    ushort8 o;
    o[0] = f2bf(a.x); o[1] = f2bf(a.y); o[2] = f2bf(a.z); o[3] = f2bf(a.w);
    o[4] = f2bf(b.x); o[5] = f2bf(b.y); o[6] = f2bf(b.z); o[7] = f2bf(b.w);
    *(ushort8*)(Xb + i) = o;
    return;
  }
  const float* src = z == 0 ? s0 : z == 1 ? s1 : z == 2 ? s2 : s3;
  unsigned short* dst = z == 0 ? d0 : z == 1 ? d1 : z == 2 ? d2 : d3;
  __shared__ float t[32][33];
  int tx = threadIdx.x, ty = threadIdx.y;
  int c0 = blockIdx.x * 32, r0 = blockIdx.y * 32;
  for (int i = ty; i < 32; i += 8)
    t[i][tx] = src[(size_t)(r0 + i) * BDIM + c0 + tx];
  __syncthreads();
  for (int i = ty; i < 32; i += 8)
    dst[(size_t)(c0 + i) * BDIM + r0 + tx] = f2bf(t[tx][i]);
}

// ---------------- GEMM body: C[M][1024] = A * W given WT[n][k]; dbuf single-barrier ----
template <bool F32OUT>
__device__ __forceinline__ void gemm_body(const unsigned short* __restrict__ A,
                                          const unsigned short* __restrict__ BT,
                                          void* __restrict__ Cv,
                                          unsigned short* As, unsigned short* Bs) {
  const int tid = threadIdx.x;
  const int lane = tid & 63;
  const int w = tid >> 6;
  const int wr = w >> 1, wc = w & 1;
  const int m0 = blockIdx.x * 128;
  const int n0 = blockIdx.y * 128;
  const int l15 = lane & 15, lg = lane >> 4;

  int ob[4], grow[4], gcol[4];
  for (int j = 0; j < 4; ++j) {
    ob[j] = (w * 4 + j) * 1024;
    int o = ob[j] + lane * 16;
    int row = o >> 7;
    int kb = (o & 127) ^ ((row & 7) << 4);
    grow[j] = row; gcol[j] = kb >> 1;
  }

  f32x4 acc[4][4] = {};

  for (int j = 0; j < 4; ++j) {
    gload16(A + (size_t)(m0 + grow[j]) * BDIM + gcol[j], (char*)As + ob[j]);
    gload16(BT + (size_t)(n0 + grow[j]) * BDIM + gcol[j], (char*)Bs + ob[j]);
  }
  __syncthreads();

  int cur = 0;
  for (int k0 = 0; k0 < BDIM; k0 += 64) {
    if (k0 + 64 < BDIM) {
      int nb = (cur ^ 1) * 16384;
      for (int j = 0; j < 4; ++j) {
        gload16(A + (size_t)(m0 + grow[j]) * BDIM + (k0 + 64) + gcol[j], (char*)As + nb + ob[j]);
        gload16(BT + (size_t)(n0 + grow[j]) * BDIM + (k0 + 64) + gcol[j], (char*)Bs + nb + ob[j]);
      }
    }
    const char* Ab = (const char*)As + cur * 16384;
    const char* Bb = (const char*)Bs + cur * 16384;
    for (int ks = 0; ks < 64; ks += 32) {
      int kb = (ks + lg * 8) * 2;
      short8 a[4], b[4];
      for (int mi = 0; mi < 4; ++mi) {
        int row = wr * 64 + mi * 16 + l15;
        a[mi] = *(const short8*)(Ab + row * 128 + (kb ^ ((row & 7) << 4)));
      }
      for (int nj = 0; nj < 4; ++nj) {
        int row = wc * 64 + nj * 16 + l15;
        b[nj] = *(const short8*)(Bb + row * 128 + (kb ^ ((row & 7) << 4)));
      }
      for (int mi = 0; mi < 4; ++mi)
        for (int nj = 0; nj < 4; ++nj)
          acc[mi][nj] = __builtin_amdgcn_mfma_f32_16x16x32_bf16(a[mi], b[nj], acc[mi][nj], 0, 0, 0);
    }
    __syncthreads();
    cur ^= 1;
  }

  for (int mi = 0; mi < 4; ++mi)
    for (int nj = 0; nj < 4; ++nj) {
      int m = m0 + wr * 64 + mi * 16 + lg * 4;
      int n = n0 + wc * 64 + nj * 16 + l15;
      for (int r = 0; r < 4; ++r) {
        if constexpr (F32OUT)
          ((float*)Cv)[(size_t)(m + r) * BDIM + n] = acc[mi][nj][r];
        else
          ((unsigned short*)Cv)[(size_t)(m + r) * BDIM + n] = f2bf(acc[mi][nj][r]);
      }
    }
}

__global__ __launch_bounds__(256) void gemm_qkv(const unsigned short* __restrict__ A,
                                                const unsigned short* __restrict__ B0,
                                                const unsigned short* __restrict__ B1,
                                                const unsigned short* __restrict__ B2,
                                                unsigned short* __restrict__ C0,
                                                unsigned short* __restrict__ C1,
                                                unsigned short* __restrict__ C2) {
  __shared__ __align__(16) unsigned short As[2 * 128 * 64];
  __shared__ __align__(16) unsigned short Bs[2 * 128 * 64];
  const unsigned short* BT = blockIdx.z == 0 ? B0 : blockIdx.z == 1 ? B1 : B2;
  unsigned short* C = blockIdx.z == 0 ? C0 : blockIdx.z == 1 ? C1 : C2;
  gemm_body<false>(A, BT, C, As, Bs);
}

template <bool F32OUT>
__global__ __launch_bounds__(256) void gemm_bt(const unsigned short* __restrict__ A,
                                               const unsigned short* __restrict__ BT,
                                               void* __restrict__ Cv) {
  __shared__ __align__(16) unsigned short As[2 * 128 * 64];
  __shared__ __align__(16) unsigned short Bs[2 * 128 * 64];
  gemm_body<F32OUT>(A, BT, Cv, As, Bs);
}

// ---------------- flash attention (causal): QBLK=256, 8 waves x 32 rows, dbuf 1-barrier --
// Merge of proven pieces: R15's dbuf single-barrier pipeline + R19's mi=2 shared-fragment
// dedup + fixed-max softmax. Per-CU: 36 tiles (vs 68), barriers halved, staging halved.
// grid (64 bh, 8): c = by<4 ? 7-by : by-4 -> CU's pair {by, by+4} sums to 36 tiles.
// LDS 64KB (Ks[2] 16 + VTs[2] 16 + Ps 32) -> 2 blocks/CU, 16 waves.
__global__ __launch_bounds__(512) void attn(const unsigned short* __restrict__ Qg,
                                            const unsigned short* __restrict__ Kg,
                                            const unsigned short* __restrict__ Vg,
                                            unsigned short* __restrict__ Og) {
  __shared__ __align__(16) unsigned short Ks[2][64 * 64];   // [kv][d]  swz (row&7)<<4
  __shared__ __align__(16) unsigned short VTs[2][64 * 64];  // [d][kv]  swzV ((d&7)^(d>>3))<<4
  __shared__ __align__(16) unsigned short Ps[256 * 64];     // [q][kv]  swz (row&7)<<4 (Q stage too)

  const int tid = threadIdx.x;
  const int lane = tid & 63;
  const int w = tid >> 6;              // 0..7
  const int l15 = lane & 15, lg = lane >> 4;
  const int bh = blockIdx.x;
  const size_t base = ((size_t)(bh >> 4) * SEQ) * BDIM + (size_t)(bh & 15) * 64;
  constexpr float C = 0.125f * 1.44269504089f;  // (1/sqrt(64)) * log2(e)
  constexpr float MB = 96.0f * C;               // fixed softmax bias (shift-invariant -> exact)

  // staging geometry: 512 thr cover 64 rows/pass
  const int srow = tid >> 3;                                    // 0..63
  const int scol = (((tid & 7) * 16) ^ ((srow & 7) << 4)) >> 1; // pre-swizzled elem col
  const int sdst = tid * 16;                                    // bytes 0..8191
  const int vp = tid & 31, vd = tid >> 5;                       // kv-pair 0..31, d-chunk 0..15
  int vdst[4];
  for (int e = 0; e < 4; ++e) {
    int d = vd * 4 + e;
    vdst[e] = d * 128 + ((4 * vp) ^ ((((d & 7) ^ (d >> 3)) & 7) << 4));
  }

  // balanced map: CU's co-resident pair {by, by+4} -> chunks (7-by, by) sum to 36 tiles
  const int by = blockIdx.y;
  const int c = by < 4 ? 7 - by : by - 4;
  const int q0 = c * 256;

  // ---- stage Q [256][64] into Ps (4 passes of 64 rows), pull frags ----
  for (int p = 0; p < 4; ++p)
    gload16(Qg + base + (size_t)(q0 + p * 64 + srow) * BDIM + scol, (char*)Ps + p * 8192 + sdst);
  __syncthreads();
  short8 qf[2][2];
  for (int mi = 0; mi < 2; ++mi) {
    int row = w * 32 + mi * 16 + l15;
    int sz = (row & 7) << 4;
    qf[mi][0] = *(const short8*)((const char*)Ps + row * 128 + ((lg * 16) ^ sz));
    qf[mi][1] = *(const short8*)((const char*)Ps + row * 128 + ((64 + lg * 16) ^ sz));
  }
  // no barrier needed: each wave's P writes land only on rows it pulled Q from

  float lrow[2] = {0.f, 0.f};
  f32x4 oacc[2][4] = {};  // [mi][di]: row d=di*16+4lg+r, col q=l15

  const int ntiles = 4 * c + 4;

  // prologue: tile 0 -> Ks[0], VTs[0]
  bf16x4 v0, v1;
  gload16(Kg + base + (size_t)(srow) * BDIM + scol, (char*)Ks[0] + sdst);
  {
    const unsigned short* vs = Vg + base + (size_t)(2 * vp) * BDIM + vd * 4;
    v0 = *(const bf16x4*)vs;
    v1 = *(const bf16x4*)(vs + BDIM);
  }
  for (int e = 0; e < 4; ++e) {
    unsigned int pk = (unsigned int)v0[e] | ((unsigned int)v1[e] << 16);
    *(unsigned int*)((char*)VTs[0] + vdst[e]) = pk;
  }
  __syncthreads();

  int cur = 0;
  for (int t = 0; t < ntiles; ++t) {
    const int kv0 = t * 64;
    const bool more = (t + 1 < ntiles);
    const bool live = kv0 <= q0 + w * 32 + 31;  // wave-uniform causal skip

    if (more) {  // issue next-tile loads into the other buffer; hide under compute
      const int nv0 = kv0 + 64;
      gload16(Kg + base + (size_t)(nv0 + srow) * BDIM + scol, (char*)Ks[cur ^ 1] + sdst);
      const unsigned short* vs = Vg + base + (size_t)(nv0 + 2 * vp) * BDIM + vd * 4;
      v0 = *(const bf16x4*)vs;
      v1 = *(const bf16x4*)(vs + BDIM);
    }

    if (live) {
      // QK^T swapped: shared kf reused for both mi
      f32x4 s2[2][4];
      __builtin_amdgcn_s_setprio(1);
      for (int kvj = 0; kvj < 4; ++kvj) {
        int row = kvj * 16 + l15;
        int sz = (row & 7) << 4;
        short8 kf0 = *(const short8*)((const char*)Ks[cur] + row * 128 + ((lg * 16) ^ sz));
        short8 kf1 = *(const short8*)((const char*)Ks[cur] + row * 128 + ((64 + lg * 16) ^ sz));
        for (int mi = 0; mi < 2; ++mi) {
          f32x4 z = {};
          z = __builtin_amdgcn_mfma_f32_16x16x32_bf16(kf0, qf[mi][0], z, 0, 0, 0);
          z = __builtin_amdgcn_mfma_f32_16x16x32_bf16(kf1, qf[mi][1], z, 0, 0, 0);
          s2[mi][kvj] = z;
        }
      }
      __builtin_amdgcn_s_setprio(0);

      for (int mi = 0; mi < 2; ++mi) {
        const int qbase = q0 + w * 32 + mi * 16;
        if (kv0 > qbase + 15) continue;  // fully-masked sub-row-block
        const int qc = qbase + l15;
        if (kv0 + 63 > qbase) {  // diagonal tile: apply causal mask
          for (int kvj = 0; kvj < 4; ++kvj)
            for (int r = 0; r < 4; ++r) {
              int kv = kv0 + kvj * 16 + 4 * lg + r;
              if (kv > qc) s2[mi][kvj][r] = NEGBIG;
            }
        }
        // fixed-bias exp (no running max); tree-sum
        float ps[4];
        for (int kvj = 0; kvj < 4; ++kvj) {
          float p0 = __builtin_amdgcn_exp2f(fmaf(s2[mi][kvj][0], C, -MB));
          float p1 = __builtin_amdgcn_exp2f(fmaf(s2[mi][kvj][1], C, -MB));
          float p2 = __builtin_amdgcn_exp2f(fmaf(s2[mi][kvj][2], C, -MB));
          float p3 = __builtin_amdgcn_exp2f(fmaf(s2[mi][kvj][3], C, -MB));
          s2[mi][kvj][0] = p0; s2[mi][kvj][1] = p1; s2[mi][kvj][2] = p2; s2[mi][kvj][3] = p3;
          ps[kvj] = (p0 + p1) + (p2 + p3);
        }
        float rs = (ps[0] + ps[1]) + (ps[2] + ps[3]);
        rs += __shfl_xor(rs, 16);
        rs += __shfl_xor(rs, 32);
        lrow[mi] += rs;
        int prow = w * 32 + mi * 16 + l15;
        int psz = (prow & 7) << 4;
        for (int kvj = 0; kvj < 4; ++kvj) {
          bf16x4 pk;
          pk[0] = f2bf(s2[mi][kvj][0]); pk[1] = f2bf(s2[mi][kvj][1]);
          pk[2] = f2bf(s2[mi][kvj][2]); pk[3] = f2bf(s2[mi][kvj][3]);
          *(bf16x4*)((char*)Ps + prow * 128 + ((kvj * 32 + lg * 8) ^ psz)) = pk;
        }
      }
      // PV: shared vf reused for both mi
      __builtin_amdgcn_s_setprio(1);
      for (int ks = 0; ks < 2; ++ks) {
        short8 pa[2], vf[4];
        for (int mi = 0; mi < 2; ++mi) {
          int prow = w * 32 + mi * 16 + l15;
          pa[mi] = *(const short8*)((const char*)Ps + prow * 128 +
                                    ((ks * 64 + lg * 16) ^ ((prow & 7) << 4)));
        }
        for (int di = 0; di < 4; ++di) {
          int d = di * 16 + l15;
          vf[di] = *(const short8*)((const char*)VTs[cur] + d * 128 +
                                    ((ks * 64 + lg * 16) ^ ((((d & 7) ^ (d >> 3)) & 7) << 4)));
        }
        for (int mi = 0; mi < 2; ++mi)
          for (int di = 0; di < 4; ++di)
            oacc[mi][di] = __builtin_amdgcn_mfma_f32_16x16x32_bf16(vf[di], pa[mi], oacc[mi][di], 0, 0, 0);
      }
      __builtin_amdgcn_s_setprio(0);
    }

    if (more) {  // V^T writes for next tile into other buffer (no reader conflict)
      for (int e = 0; e < 4; ++e) {
        unsigned int pk = (unsigned int)v0[e] | ((unsigned int)v1[e] << 16);
        *(unsigned int*)((char*)VTs[cur ^ 1] + vdst[e]) = pk;
      }
    }
    __syncthreads();  // single barrier: flips buffers, drains K gloads + VT writes
    cur ^= 1;
  }

  // epilogue: lane col q, rows d=di*16+4lg+r -> b64 stores
  for (int mi = 0; mi < 2; ++mi) {
    float inv = 1.0f / lrow[mi];
    int qrow = q0 + w * 32 + mi * 16 + l15;
    for (int di = 0; di < 4; ++di) {
      bf16x4 ov;
      for (int r = 0; r < 4; ++r) ov[r] = f2bf(oacc[mi][di][r] * inv);
      *(bf16x4*)(Og + base + (size_t)qrow * BDIM + di * 16 + 4 * lg) = ov;
    }
  }
}

extern "C" void kernel_launch(void* const* d_in, const int* in_sizes, int n_in,
                              void* d_out, int out_size, void* d_ws, size_t ws_size,
                              hipStream_t stream) {
  const float* X  = (const float*)d_in[0];
  const float* Wq = (const float*)d_in[1];
  const float* Wk = (const float*)d_in[2];
  const float* Wv = (const float*)d_in[3];
  const float* Wo = (const float*)d_in[4];

  const size_t WSZ = (size_t)1024 * 1024;
  const size_t MSZ = (size_t)8192 * 1024;
  const size_t need = (4 * WSZ + 4 * MSZ) * 2;  // 72 MB
  if (ws_size < need) return;

  unsigned short* ws = (unsigned short*)d_ws;
  unsigned short* WqT = ws;
  unsigned short* WkT = WqT + WSZ;
  unsigned short* WvT = WkT + WSZ;
  unsigned short* WoT = WvT + WSZ;
  unsigned short* Qw  = WoT + WSZ;
  unsigned short* Kw  = Qw + MSZ;
  unsigned short* Vw  = Kw + MSZ;
  unsigned short* Ow  = Vw + MSZ;
  unsigned short* Xb  = (unsigned short*)d_out;  // scratch; dead before final GEMM

  prep<<<dim3(32, 32, 8), dim3(32, 8), 0, stream>>>(X, Xb, Wq, Wk, Wv, Wo, WqT, WkT, WvT, WoT);

  gemm_qkv<<<dim3(64, 8, 3), 256, 0, stream>>>(Xb, WqT, WkT, WvT, Qw, Kw, Vw);

  attn<<<dim3(64, 8), 512, 0, stream>>>(Qw, Kw, Vw, Ow);

  gemm_bt<true><<<dim3(64, 8), 256, 0, stream>>>(Ow, WoT, d_out);
}

// Round 21
// 167.155 us; speedup vs baseline: 1.0132x; 1.0132x over previous
//
#include <hip/hip_runtime.h>
#include <hip/hip_bf16.h>

typedef __attribute__((ext_vector_type(8))) short short8;
typedef __attribute__((ext_vector_type(8))) unsigned short ushort8;
typedef __attribute__((ext_vector_type(4))) unsigned short bf16x4;
typedef __attribute__((ext_vector_type(4))) float f32x4;

#define BDIM 1024
#define SEQ  2048
#define NHD  16
#define NEGBIG (-1.0e30f)

__device__ __forceinline__ unsigned short f2bf(float x) {
  union { __hip_bfloat16 h; unsigned short u; } cv;
  cv.h = __float2bfloat16(x);
  return cv.u;
}

__device__ __forceinline__ void gload16(const void* g, void* l) {
  __builtin_amdgcn_global_load_lds((const __attribute__((address_space(1))) void*)g,
                                   (__attribute__((address_space(3))) void*)l, 16, 0, 0);
}

// ---------------- fused prep: z=0..3 weight transpose+cvt; z=4..7 X f32->bf16 ----------
__global__ __launch_bounds__(256) void prep(const float* __restrict__ X, unsigned short* __restrict__ Xb,
                                            const float* __restrict__ s0, const float* __restrict__ s1,
                                            const float* __restrict__ s2, const float* __restrict__ s3,
                                            unsigned short* __restrict__ d0, unsigned short* __restrict__ d1,
                                            unsigned short* __restrict__ d2, unsigned short* __restrict__ d3) {
  const int z = blockIdx.z;
  const int tid = threadIdx.y * 32 + threadIdx.x;
  if (z >= 4) {  // cvt: 1024 blocks/slice x 2048 elems
    int i = (((z - 4) * 1024 + blockIdx.y * 32 + blockIdx.x) * 256 + tid) * 8;
    float4 a = *(const float4*)(X + i);
    float4 b = *(const float4*)(X + i + 4);
    ushort8 o;
    o[0] = f2bf(a.x); o[1] = f2bf(a.y); o[2] = f2bf(a.z); o[3] = f2bf(a.w);
    o[4] = f2bf(b.x); o[5] = f2bf(b.y); o[6] = f2bf(b.z); o[7] = f2bf(b.w);
    *(ushort8*)(Xb + i) = o;
    return;
  }
  const float* src = z == 0 ? s0 : z == 1 ? s1 : z == 2 ? s2 : s3;
  unsigned short* dst = z == 0 ? d0 : z == 1 ? d1 : z == 2 ? d2 : d3;
  __shared__ float t[32][33];
  int tx = threadIdx.x, ty = threadIdx.y;
  int c0 = blockIdx.x * 32, r0 = blockIdx.y * 32;
  for (int i = ty; i < 32; i += 8)
    t[i][tx] = src[(size_t)(r0 + i) * BDIM + c0 + tx];
  __syncthreads();
  for (int i = ty; i < 32; i += 8)
    dst[(size_t)(c0 + i) * BDIM + r0 + tx] = f2bf(t[tx][i]);
}

// ---------------- GEMM body: C[M][1024] = A * W given WT[n][k]; dbuf single-barrier ----
template <bool F32OUT>
__device__ __forceinline__ void gemm_body(const unsigned short* __restrict__ A,
                                          const unsigned short* __restrict__ BT,
                                          void* __restrict__ Cv,
                                          unsigned short* As, unsigned short* Bs) {
  const int tid = threadIdx.x;
  const int lane = tid & 63;
  const int w = tid >> 6;
  const int wr = w >> 1, wc = w & 1;
  const int m0 = blockIdx.x * 128;
  const int n0 = blockIdx.y * 128;
  const int l15 = lane & 15, lg = lane >> 4;

  int ob[4], grow[4], gcol[4];
  for (int j = 0; j < 4; ++j) {
    ob[j] = (w * 4 + j) * 1024;
    int o = ob[j] + lane * 16;
    int row = o >> 7;
    int kb = (o & 127) ^ ((row & 7) << 4);
    grow[j] = row; gcol[j] = kb >> 1;
  }

  f32x4 acc[4][4] = {};

  for (int j = 0; j < 4; ++j) {
    gload16(A + (size_t)(m0 + grow[j]) * BDIM + gcol[j], (char*)As + ob[j]);
    gload16(BT + (size_t)(n0 + grow[j]) * BDIM + gcol[j], (char*)Bs + ob[j]);
  }
  __syncthreads();

  int cur = 0;
  for (int k0 = 0; k0 < BDIM; k0 += 64) {
    if (k0 + 64 < BDIM) {
      int nb = (cur ^ 1) * 16384;
      for (int j = 0; j < 4; ++j) {
        gload16(A + (size_t)(m0 + grow[j]) * BDIM + (k0 + 64) + gcol[j], (char*)As + nb + ob[j]);
        gload16(BT + (size_t)(n0 + grow[j]) * BDIM + (k0 + 64) + gcol[j], (char*)Bs + nb + ob[j]);
      }
    }
    const char* Ab = (const char*)As + cur * 16384;
    const char* Bb = (const char*)Bs + cur * 16384;
    for (int ks = 0; ks < 64; ks += 32) {
      int kb = (ks + lg * 8) * 2;
      short8 a[4], b[4];
      for (int mi = 0; mi < 4; ++mi) {
        int row = wr * 64 + mi * 16 + l15;
        a[mi] = *(const short8*)(Ab + row * 128 + (kb ^ ((row & 7) << 4)));
      }
      for (int nj = 0; nj < 4; ++nj) {
        int row = wc * 64 + nj * 16 + l15;
        b[nj] = *(const short8*)(Bb + row * 128 + (kb ^ ((row & 7) << 4)));
      }
      for (int mi = 0; mi < 4; ++mi)
        for (int nj = 0; nj < 4; ++nj)
          acc[mi][nj] = __builtin_amdgcn_mfma_f32_16x16x32_bf16(a[mi], b[nj], acc[mi][nj], 0, 0, 0);
    }
    __syncthreads();
    cur ^= 1;
  }

  for (int mi = 0; mi < 4; ++mi)
    for (int nj = 0; nj < 4; ++nj) {
      int m = m0 + wr * 64 + mi * 16 + lg * 4;
      int n = n0 + wc * 64 + nj * 16 + l15;
      for (int r = 0; r < 4; ++r) {
        if constexpr (F32OUT)
          ((float*)Cv)[(size_t)(m + r) * BDIM + n] = acc[mi][nj][r];
        else
          ((unsigned short*)Cv)[(size_t)(m + r) * BDIM + n] = f2bf(acc[mi][nj][r]);
      }
    }
}

__global__ __launch_bounds__(256) void gemm_qkv(const unsigned short* __restrict__ A,
                                                const unsigned short* __restrict__ B0,
                                                const unsigned short* __restrict__ B1,
                                                const unsigned short* __restrict__ B2,
                                                unsigned short* __restrict__ C0,
                                                unsigned short* __restrict__ C1,
                                                unsigned short* __restrict__ C2) {
  __shared__ __align__(16) unsigned short As[2 * 128 * 64];
  __shared__ __align__(16) unsigned short Bs[2 * 128 * 64];
  const unsigned short* BT = blockIdx.z == 0 ? B0 : blockIdx.z == 1 ? B1 : B2;
  unsigned short* C = blockIdx.z == 0 ? C0 : blockIdx.z == 1 ? C1 : C2;
  gemm_body<false>(A, BT, C, As, Bs);
}

template <bool F32OUT>
__global__ __launch_bounds__(256) void gemm_bt(const unsigned short* __restrict__ A,
                                               const unsigned short* __restrict__ BT,
                                               void* __restrict__ Cv) {
  __shared__ __align__(16) unsigned short As[2 * 128 * 64];
  __shared__ __align__(16) unsigned short Bs[2 * 128 * 64];
  gemm_body<F32OUT>(A, BT, Cv, As, Bs);
}

// ---------------- flash attention (causal): R15 config (best measured, 82.5us) ----------
// QBLK=128, 8 waves x 16 q-rows; grid (64 bh, 16) LPT single chunks; dbuf K/VT with ONE
// barrier per tile; 48KB LDS -> 3 blocks/CU; running-max softmax w/ exact defer (v_exp_f32).
__global__ __launch_bounds__(512) void attn(const unsigned short* __restrict__ Qg,
                                            const unsigned short* __restrict__ Kg,
                                            const unsigned short* __restrict__ Vg,
                                            unsigned short* __restrict__ Og) {
  __shared__ __align__(16) unsigned short Ks[2][64 * 64];   // [kv][d]  swz (row&7)<<4
  __shared__ __align__(16) unsigned short VTs[2][64 * 64];  // [d][kv]  swzV ((d&7)^(d>>3))<<4
  __shared__ __align__(16) unsigned short Ps[128 * 64];     // [q][kv]  swz (row&7)<<4 (Q stage too)

  const int tid = threadIdx.x;
  const int lane = tid & 63;
  const int w = tid >> 6;              // 0..7
  const int l15 = lane & 15, lg = lane >> 4;
  const int bh = blockIdx.x;
  const size_t base = ((size_t)(bh >> 4) * SEQ) * BDIM + (size_t)(bh & 15) * 64;
  constexpr float C = 0.125f * 1.44269504089f;  // (1/sqrt(64)) * log2(e)

  const int srow = tid >> 3;
  const int scol = (((tid & 7) * 16) ^ ((srow & 7) << 4)) >> 1;
  const int sdst = tid * 16;
  const int vp = tid & 31, vd = tid >> 5;
  int vdst[4];
  for (int e = 0; e < 4; ++e) {
    int d = vd * 4 + e;
    vdst[e] = d * 128 + ((4 * vp) ^ ((((d & 7) ^ (d >> 3)) & 7) << 4));
  }

  const int c = 15 - (int)blockIdx.y;  // LPT: longest chunks dispatch first
  const int q0 = c * 128;

  gload16(Qg + base + (size_t)(q0 + srow) * BDIM + scol, (char*)Ps + sdst);
  gload16(Qg + base + (size_t)(q0 + 64 + srow) * BDIM + scol, (char*)Ps + 8192 + sdst);
  __syncthreads();
  short8 qf[2];
  {
    int row = w * 16 + l15;
    int sz = (row & 7) << 4;
    qf[0] = *(const short8*)((const char*)Ps + row * 128 + ((lg * 16) ^ sz));
    qf[1] = *(const short8*)((const char*)Ps + row * 128 + ((64 + lg * 16) ^ sz));
  }

  float mrow = NEGBIG, lrow = 0.f;
  f32x4 oacc[4] = {};  // [di]: row d=di*16+4lg+r, col q=l15

  const int ntiles = 2 * c + 2;

  // prologue: tile 0 -> Ks[0], VTs[0]
  bf16x4 v0, v1;
  gload16(Kg + base + (size_t)(srow) * BDIM + scol, (char*)Ks[0] + sdst);
  {
    const unsigned short* vs = Vg + base + (size_t)(2 * vp) * BDIM + vd * 4;
    v0 = *(const bf16x4*)vs;
    v1 = *(const bf16x4*)(vs + BDIM);
  }
  for (int e = 0; e < 4; ++e) {
    unsigned int pk = (unsigned int)v0[e] | ((unsigned int)v1[e] << 16);
    *(unsigned int*)((char*)VTs[0] + vdst[e]) = pk;
  }
  __syncthreads();

  int cur = 0;
  for (int t = 0; t < ntiles; ++t) {
    const int kv0 = t * 64;
    const bool more = (t + 1 < ntiles);
    if (more) {  // issue next-tile loads; latency hides under compute below
      const int nv0 = kv0 + 64;
      gload16(Kg + base + (size_t)(nv0 + srow) * BDIM + scol, (char*)Ks[cur ^ 1] + sdst);
      const unsigned short* vs = Vg + base + (size_t)(nv0 + 2 * vp) * BDIM + vd * 4;
      v0 = *(const bf16x4*)vs;
      v1 = *(const bf16x4*)(vs + BDIM);
    }

    if (kv0 <= q0 + w * 16 + 15) {  // wave-uniform causal skip
      f32x4 s2[4];
      __builtin_amdgcn_s_setprio(1);
      for (int kvj = 0; kvj < 4; ++kvj) {
        int row = kvj * 16 + l15;
        int sz = (row & 7) << 4;
        short8 kf0 = *(const short8*)((const char*)Ks[cur] + row * 128 + ((lg * 16) ^ sz));
        short8 kf1 = *(const short8*)((const char*)Ks[cur] + row * 128 + ((64 + lg * 16) ^ sz));
        f32x4 z = {};
        z = __builtin_amdgcn_mfma_f32_16x16x32_bf16(kf0, qf[0], z, 0, 0, 0);
        z = __builtin_amdgcn_mfma_f32_16x16x32_bf16(kf1, qf[1], z, 0, 0, 0);
        s2[kvj] = z;
      }
      __builtin_amdgcn_s_setprio(0);
      const int qbase = q0 + w * 16;
      const int qc = qbase + l15;
      float mx = NEGBIG;
      if (kv0 + 63 > qbase) {  // diagonal tile: apply causal mask
        for (int kvj = 0; kvj < 4; ++kvj)
          for (int r = 0; r < 4; ++r) {
            int kv = kv0 + kvj * 16 + 4 * lg + r;
            float v = s2[kvj][r];
            if (kv > qc) { v = NEGBIG; s2[kvj][r] = v; }
            mx = fmaxf(mx, v);
          }
      } else {
        for (int kvj = 0; kvj < 4; ++kvj)
          for (int r = 0; r < 4; ++r) mx = fmaxf(mx, s2[kvj][r]);
      }
      mx = fmaxf(mx, __shfl_xor(mx, 16));
      mx = fmaxf(mx, __shfl_xor(mx, 32));
      if (!__all(mx <= mrow)) {  // else sc==1 exactly: skip rescale
        float mnew = fmaxf(mrow, mx);
        float sc = __builtin_amdgcn_exp2f((mrow - mnew) * C);
        mrow = mnew;
        lrow *= sc;
        for (int di = 0; di < 4; ++di)
          for (int r = 0; r < 4; ++r) oacc[di][r] *= sc;
      }
      const float mC = mrow * C;
      float rs = 0.f;
      for (int kvj = 0; kvj < 4; ++kvj)
        for (int r = 0; r < 4; ++r) {
          float p = __builtin_amdgcn_exp2f(fmaf(s2[kvj][r], C, -mC));  // masked -> 0
          s2[kvj][r] = p;
          rs += p;
        }
      rs += __shfl_xor(rs, 16);
      rs += __shfl_xor(rs, 32);
      lrow += rs;
      int prow = w * 16 + l15;
      int psz = (prow & 7) << 4;
      for (int kvj = 0; kvj < 4; ++kvj) {
        bf16x4 pk;
        pk[0] = f2bf(s2[kvj][0]); pk[1] = f2bf(s2[kvj][1]);
        pk[2] = f2bf(s2[kvj][2]); pk[3] = f2bf(s2[kvj][3]);
        *(bf16x4*)((char*)Ps + prow * 128 + ((kvj * 32 + lg * 8) ^ psz)) = pk;
      }
      __builtin_amdgcn_s_setprio(1);
      for (int ks = 0; ks < 2; ++ks) {
        short8 pa = *(const short8*)((const char*)Ps + prow * 128 +
                                     ((ks * 64 + lg * 16) ^ psz));
        for (int di = 0; di < 4; ++di) {
          int d = di * 16 + l15;
          short8 vf = *(const short8*)((const char*)VTs[cur] + d * 128 +
                                       ((ks * 64 + lg * 16) ^ ((((d & 7) ^ (d >> 3)) & 7) << 4)));
          oacc[di] = __builtin_amdgcn_mfma_f32_16x16x32_bf16(vf, pa, oacc[di], 0, 0, 0);
        }
      }
      __builtin_amdgcn_s_setprio(0);
    }

    if (more) {  // V^T writes for next tile
      for (int e = 0; e < 4; ++e) {
        unsigned int pk = (unsigned int)v0[e] | ((unsigned int)v1[e] << 16);
        *(unsigned int*)((char*)VTs[cur ^ 1] + vdst[e]) = pk;
      }
    }
    __syncthreads();  // flips buffers; drains vmcnt (gload_lds) + lgkm
    cur ^= 1;
  }

  // epilogue
  {
    float inv = 1.0f / lrow;
    int qrow = q0 + w * 16 + l15;
    for (int di = 0; di < 4; ++di) {
      bf16x4 ov;
      for (int r = 0; r < 4; ++r) ov[r] = f2bf(oacc[di][r] * inv);
      *(bf16x4*)(Og + base + (size_t)qrow * BDIM + di * 16 + 4 * lg) = ov;
    }
  }
}

extern "C" void kernel_launch(void* const* d_in, const int* in_sizes, int n_in,
                              void* d_out, int out_size, void* d_ws, size_t ws_size,
                              hipStream_t stream) {
  const float* X  = (const float*)d_in[0];
  const float* Wq = (const float*)d_in[1];
  const float* Wk = (const float*)d_in[2];
  const float* Wv = (const float*)d_in[3];
  const float* Wo = (const float*)d_in[4];

  const size_t WSZ = (size_t)1024 * 1024;
  const size_t MSZ = (size_t)8192 * 1024;
  const size_t need = (4 * WSZ + 4 * MSZ) * 2;  // 72 MB
  if (ws_size < need) return;

  unsigned short* ws = (unsigned short*)d_ws;
  unsigned short* WqT = ws;
  unsigned short* WkT = WqT + WSZ;
  unsigned short* WvT = WkT + WSZ;
  unsigned short* WoT = WvT + WSZ;
  unsigned short* Qw  = WoT + WSZ;
  unsigned short* Kw  = Qw + MSZ;
  unsigned short* Vw  = Kw + MSZ;
  unsigned short* Ow  = Vw + MSZ;
  unsigned short* Xb  = (unsigned short*)d_out;  // scratch; dead before final GEMM

  prep<<<dim3(32, 32, 8), dim3(32, 8), 0, stream>>>(X, Xb, Wq, Wk, Wv, Wo, WqT, WkT, WvT, WoT);

  gemm_qkv<<<dim3(64, 8, 3), 256, 0, stream>>>(Xb, WqT, WkT, WvT, Qw, Kw, Vw);

  attn<<<dim3(64, 16), 512, 0, stream>>>(Qw, Kw, Vw, Ow);

  gemm_bt<true><<<dim3(64, 8), 256, 0, stream>>>(Ow, WoT, d_out);
}